// Round 10
// baseline (474.402 us; speedup 1.0000x reference)
//
#include <hip/hip_runtime.h>
#include <hip/hip_bf16.h>
#include <math.h>

// ---------------------------------------------------------------------------
// GAT 3-layer forward on MI355X.
//   R18 (fix round):
//   - RACE FIX: R17 passed as_/ad_ as both asrc/adst (read N x 8 all loop)
//     and out_as3/out_ad3 (written N x 1 at wave end) in agg8c8 -> blocks
//     finishing early corrupted data still being read (absmax 0.0156->0.031,
//     nondeterministic). alpha3 now writes fresh as3_/ad3_ buffers.
//   - agg1h evals cache REVERTED: layer-3 asrc is 400 KB (L2-resident);
//     the cache added 12.8 MB traffic for nothing (wrong traffic model).
//   - gemm3-into-agg8c8 fusion KEPT (net -7 us with race fixed; z computed
//     from f32 h2 = strictly closer to reference than old bf16 round-trip).
//   - agg16 CLOSED: ~4.8 TB/s effective random-gather (fabric ceiling),
//     scheduling-invariant across 4 variants. Do not re-attack.
//   R15/R16: K-split L1 staging, part+prep / csr+gemm1 fusions,
//   LDS-C-tile epilogue (R14), sched_barrier pins (neutral, kept).
// ---------------------------------------------------------------------------

#define LEAKY(v) ((v) > 0.f ? (v) : 0.2f * (v))

typedef __bf16 bf16_t;
typedef __bf16 bf16x8 __attribute__((ext_vector_type(8)));
typedef __bf16 bf16x4 __attribute__((ext_vector_type(4)));
typedef float f32x4 __attribute__((ext_vector_type(4)));
typedef unsigned short u16x8 __attribute__((ext_vector_type(8)));

static __device__ __forceinline__ unsigned short bf_bits(float f) {
    bf16_t b = (bf16_t)f;
    return __builtin_bit_cast(unsigned short, b);
}
static __device__ __forceinline__ float bf_to_f(unsigned short u) {
    return __uint_as_float(((unsigned int)u) << 16);
}
static __device__ __forceinline__ float bperm_f(int byteaddr, float v) {
    return __uint_as_float((unsigned)__builtin_amdgcn_ds_bpermute(byteaddr, (int)__float_as_uint(v)));
}

// ---------------- CSR build: 2-pass bucket sort ----------------
constexpr int NB_MAX = 400;
constexpr int BCAP = 5120;  // capacity per bucket region; mean load 4096

// ---------------- W pre-pack device helpers ----------------
static __device__ __forceinline__ void prep_w_dev(
        const float* __restrict__ W, short* __restrict__ Bfs,
        int K, int N, int NT, int idx) {
    int lane = idx & 63;
    int t = idx >> 6;
    int ntile = t % NT, kstep = t / NT;
    int quad = lane >> 4, nl = lane & 15;
    int n = ntile * 16 + nl;
    bf16_t* dst = (bf16_t*)Bfs + (size_t)idx * 16;
#pragma unroll
    for (int j = 0; j < 8; j++) {
        int k = kstep * 32 + quad * 8 + j;
        float v = W[k * N + n];
        bf16_t h = (bf16_t)v;
        bf16_t l = (bf16_t)(v - (float)h);
        dst[j] = h;
        dst[8 + j] = l;
    }
}

// ---------------- fused: edge partition + W pre-pack ----------------
__global__ __launch_bounds__(256) void part_prep_k(
        const int* __restrict__ src, const int* __restrict__ dst, int E, int NB,
        int* __restrict__ bcur, unsigned* __restrict__ staged, int PB,
        const float* __restrict__ W1, const float* __restrict__ W2,
        short* __restrict__ Bf1, short* __restrict__ Bf2) {
    __shared__ int hist[NB_MAX];
    __shared__ int bstart[NB_MAX + 1];
    __shared__ int cur[NB_MAX];
    __shared__ int gbase[NB_MAX];
    __shared__ unsigned words[4096];
    __shared__ unsigned short bidl[4096];
    int tid = threadIdx.x;

    if ((int)blockIdx.x >= PB) {  // ---- prep branch ----
        int idx = ((int)blockIdx.x - PB) * 256 + tid;
        if (idx < 4096) prep_w_dev(W1, Bf1, 256, 128, 8, idx);
        else if (idx < 5120) prep_w_dev(W2, Bf2, 128, 64, 4, idx - 4096);
        return;
    }

    int e0 = blockIdx.x * 4096;
    int cnt = E - e0; if (cnt > 4096) cnt = 4096;
    if (cnt <= 0) return;

    for (int b = tid; b < NB; b += 256) hist[b] = 0;
    __syncthreads();
    for (int i = tid; i < cnt; i += 256) atomicAdd(&hist[dst[e0 + i] >> 8], 1);
    __syncthreads();
    // wave-0 parallel exclusive scan over NB entries
    if (tid < 64) {
        int lane = tid;
        int run = 0;
        for (int b0 = 0; b0 < NB; b0 += 64) {
            int bb = b0 + lane;
            int v = (bb < NB) ? hist[bb] : 0;
            int sc = v;
            for (int off = 1; off < 64; off <<= 1) {
                int t2 = __shfl_up(sc, off, 64);
                if (lane >= off) sc += t2;
            }
            if (bb < NB) bstart[bb] = run + sc - v;
            run += __shfl(sc, 63, 64);
        }
        if (lane == 0) bstart[NB] = run;
    }
    __syncthreads();
    for (int b = tid; b < NB; b += 256) {
        cur[b] = bstart[b];
        gbase[b] = hist[b] ? atomicAdd(&bcur[b], hist[b]) : 0;
    }
    __syncthreads();
    // group into LDS by bucket, remember bucket id per slot
    for (int i = tid; i < cnt; i += 256) {
        int s = src[e0 + i], d = dst[e0 + i];
        int b = d >> 8;
        unsigned w = (unsigned)s | ((unsigned)(d & 255) << 17);
        int p = atomicAdd(&cur[b], 1);
        words[p] = w;
        bidl[p] = (unsigned short)b;
    }
    __syncthreads();
    // linear sweep -> coalesced runs into global bucket regions
    for (int i = tid; i < cnt; i += 256) {
        int b = bidl[i];
        staged[(size_t)b * BCAP + gbase[b] + (i - bstart[b])] = words[i];
    }
}

// ---------------- buildcsr body (runs inside fused csr_gemm1_k) ----------------
static __device__ void buildcsr_body(
        char* smem, const unsigned* __restrict__ staged, const int* __restrict__ bcur,
        int* __restrict__ offs, int* __restrict__ cols, int N, int NB, int b) {
    int* h    = (int*)smem;
    int* hs   = h + 256;
    int* curl = hs + 256;
    int* colsl = curl + 256;
    int* base_p = colsl + BCAP;
    int tid = threadIdx.x;
    int n0 = b << 8;
    int ecnt = bcur[b];
    const unsigned* sb = staged + (size_t)b * BCAP;

    h[tid] = 0;
    if (tid < 64) {  // base_g = sum(bcur[0..b))
        int acc2 = 0;
        for (int i = tid; i < b; i += 64) acc2 += bcur[i];
        for (int off = 1; off < 64; off <<= 1) acc2 += __shfl_xor(acc2, off, 64);
        if (tid == 0) *base_p = acc2;
    }
    __syncthreads();
    int base_g = *base_p;
    for (int i = tid; i < ecnt; i += 256) atomicAdd(&h[sb[i] >> 17], 1);
    __syncthreads();
    int val = h[tid];
    hs[tid] = val; __syncthreads();
    for (int off = 1; off < 256; off <<= 1) {
        int t = (tid >= off) ? hs[tid - off] : 0;
        __syncthreads();
        hs[tid] += t;
        __syncthreads();
    }
    int excl = hs[tid] - val;
    curl[tid] = excl;
    if (n0 + tid < N) offs[n0 + tid] = base_g + excl;
    if (b == NB - 1 && tid == 0) offs[N] = base_g + ecnt;
    __syncthreads();
    for (int i = tid; i < ecnt; i += 256) {
        unsigned w = sb[i];
        int p = atomicAdd(&curl[w >> 17], 1);
        colsl[p] = (int)(w & 0x1FFFFu);
    }
    __syncthreads();
    for (int i = tid; i < ecnt; i += 256) cols[base_g + i] = colsl[i];
}

// ---------------- split-bf16 MFMA GEMM body (K-split staging + epilogue v2) ----------------
template <int BM, int WMT, int WNT, int NWM, bool ABF16, int CHEAD, int K, int NPH>
static __device__ __forceinline__ void gemm_body(
        char* smem,
        const void* __restrict__ Av, const short* __restrict__ Bfs,
        unsigned short* __restrict__ Cb,
        const float* __restrict__ a_s, const float* __restrict__ a_d,
        float* __restrict__ out_as, float* __restrict__ out_ad,
        int M, int N, int NT, int bx, int by) {
    constexpr int NWN = 4 / NWM;
    constexpr int BN = 16 * WNT * NWN;
    constexpr int KPH = K / NPH;     // K per staging phase
    constexpr int KPP = KPH + 8;     // +8 bf16 pad: breaks bank aliasing
    constexpr int BNP = BN + 2;      // f32 C-tile pad
    bf16_t* As_hi = (bf16_t*)smem;
    bf16_t* As_lo = As_hi + (ABF16 ? 0 : (size_t)BM * KPP);
    float* Ct = (float*)smem;
    const bf16_t* Bf = (const bf16_t*)Bfs;

    int tid = threadIdx.x;
    int wave = tid >> 6, lane = tid & 63;
    int quad = lane >> 4, l16 = lane & 15;
    int wm = wave % NWM, wn = wave / NWM;
    int row0 = bx * BM;
    int ntile0 = by * (BN / 16) + wn * WNT;

    f32x4 acc[WMT][WNT];
#pragma unroll
    for (int i = 0; i < WMT; i++)
#pragma unroll
        for (int j = 0; j < WNT; j++) acc[i][j] = (f32x4){0.f, 0.f, 0.f, 0.f};

#pragma unroll
    for (int phase = 0; phase < NPH; phase++) {
        if (phase) __syncthreads();  // previous compute's LDS reads done
        // ---- stage this K-phase: all loads issued before conversion ----
        if constexpr (!ABF16) {
            constexpr int CHUNKS = BM * KPH * 4 / (16 * 256);
            const float* A = (const float*)Av;
            f32x4 tmp[CHUNKS];
#pragma unroll
            for (int c = 0; c < CHUNKS; c++) {
                int ci = c * 256 + tid;
                int fi = ci * 4;
                int row = fi / KPH, k = fi % KPH;
                int grow = row0 + row;
                tmp[c] = (f32x4){0.f, 0.f, 0.f, 0.f};
                if (grow < M) tmp[c] = *(const f32x4*)(A + (size_t)grow * K + phase * KPH + k);
            }
#pragma unroll
            for (int c = 0; c < CHUNKS; c++) {
                int ci = c * 256 + tid;
                int fi = ci * 4;
                int row = fi / KPH, k = fi % KPH;
                bf16x4 h, l;
#pragma unroll
                for (int j = 0; j < 4; j++) {
                    bf16_t hh = (bf16_t)tmp[c][j];
                    h[j] = hh;
                    l[j] = (bf16_t)(tmp[c][j] - (float)hh);
                }
                *(bf16x4*)&As_hi[row * KPP + k] = h;
                *(bf16x4*)&As_lo[row * KPP + k] = l;
            }
        } else {
            constexpr int CHUNKS = BM * KPH * 2 / (16 * 256);
            const unsigned short* A = (const unsigned short*)Av;
            u16x8 tmp[CHUNKS];
#pragma unroll
            for (int c = 0; c < CHUNKS; c++) {
                int ci = c * 256 + tid;
                int ei = ci * 8;
                int row = ei / KPH, k = ei % KPH;
                int grow = row0 + row;
                tmp[c] = (u16x8){0, 0, 0, 0, 0, 0, 0, 0};
                if (grow < M) tmp[c] = *(const u16x8*)(A + (size_t)grow * K + phase * KPH + k);
            }
#pragma unroll
            for (int c = 0; c < CHUNKS; c++) {
                int ci = c * 256 + tid;
                int ei = ci * 8;
                int row = ei / KPH, k = ei % KPH;
                *(u16x8*)&As_hi[row * KPP + k] = tmp[c];
            }
        }
        __syncthreads();

        // ---- compute this K-phase (barrier-free) ----
#pragma unroll
        for (int ks = 0; ks < KPH / 32; ks++) {
            int ksg = phase * (KPH / 32) + ks;
            bf16x8 ah[WMT], al[WMT];
#pragma unroll
            for (int i = 0; i < WMT; i++) {
                int rowl = wm * (WMT * 16) + i * 16 + l16;
                ah[i] = *(const bf16x8*)&As_hi[rowl * KPP + ks * 32 + quad * 8];
                if (!ABF16) al[i] = *(const bf16x8*)&As_lo[rowl * KPP + ks * 32 + quad * 8];
            }
            bf16x8 bh[WNT], bl[WNT];
#pragma unroll
            for (int j = 0; j < WNT; j++) {
                size_t base = ((size_t)(ksg * NT + ntile0 + j) * 64 + lane) * 16;
                bh[j] = *(const bf16x8*)&Bf[base];
                bl[j] = *(const bf16x8*)&Bf[base + 8];
            }
#pragma unroll
            for (int i = 0; i < WMT; i++)
#pragma unroll
                for (int j = 0; j < WNT; j++) {
                    acc[i][j] = __builtin_amdgcn_mfma_f32_16x16x32_bf16(ah[i], bh[j], acc[i][j], 0, 0, 0);
                    if (!ABF16)
                        acc[i][j] = __builtin_amdgcn_mfma_f32_16x16x32_bf16(al[i], bh[j], acc[i][j], 0, 0, 0);
                    acc[i][j] = __builtin_amdgcn_mfma_f32_16x16x32_bf16(ah[i], bl[j], acc[i][j], 0, 0, 0);
                }
        }
    }

    // ---- epilogue v2: acc -> LDS f32 C-tile, then alpha + coalesced C ----
    __syncthreads();  // all As reads done before overwrite
#pragma unroll
    for (int i = 0; i < WMT; i++) {
        int rbase = wm * (WMT * 16) + i * 16 + quad * 4;  // block-local row
#pragma unroll
        for (int j = 0; j < WNT; j++) {
            int lcol = (wn * WNT + j) * 16 + l16;          // block-local col
#pragma unroll
            for (int r2 = 0; r2 < 4; r2++)
                Ct[(size_t)(rbase + r2) * BNP + lcol] = acc[i][j][r2];
        }
    }
    __syncthreads();

    // phase 2a: alpha — BM x (BN/CHEAD) outputs, contiguous LDS reads
    constexpr int HB = BN / CHEAD;
    const int colbase = by * BN;
    const int Hh = N / CHEAD;
#pragma unroll
    for (int o = 0; o < (BM * HB + 255) / 256; o++) {
        int idx = o * 256 + tid;
        if (idx < BM * HB) {
            int row = idx & (BM - 1);
            int hd = idx / BM;   // wave-uniform -> scalar a_s/a_d loads
            const float* crow = Ct + (size_t)row * BNP + hd * CHEAD;
            float ss = 0.f, sd = 0.f;
#pragma unroll
            for (int c = 0; c < CHEAD; c++) {
                float v = crow[c];
                ss = fmaf(v, a_s[colbase + hd * CHEAD + c], ss);
                sd = fmaf(v, a_d[colbase + hd * CHEAD + c], sd);
            }
            int grow = row0 + row;
            if (grow < M) {
                out_as[(size_t)grow * Hh + by * HB + hd] = ss;
                out_ad[(size_t)grow * Hh + by * HB + hd] = sd;
            }
        }
    }

    // phase 2b: C store — packed 2xbf16, coalesced 4B/lane
    constexpr int CU2 = BM * BN / 2;  // uint count (multiple of 256 here)
#pragma unroll
    for (int o = 0; o < CU2 / 256; o++) {
        int idx = o * 256 + tid;
        int row = idx / (BN / 2);
        int uc = idx - row * (BN / 2);
        float v0 = Ct[(size_t)row * BNP + uc * 2];
        float v1 = Ct[(size_t)row * BNP + uc * 2 + 1];
        unsigned pk = (unsigned)bf_bits(v0) | ((unsigned)bf_bits(v1) << 16);
        int grow = row0 + row;
        if (grow < M)
            ((unsigned*)Cb)[((size_t)grow * N + colbase) / 2 + uc] = pk;
    }
}

// ---------------- fused: buildcsr + layer-1 GEMM ----------------
constexpr int SMEM1 = 64 * (128 + 8) * 2 * 2;  // 34816 >= max(ASZ, CSZ, CSR)
__global__ __launch_bounds__(256, 3) void csr_gemm1_k(
        const unsigned* __restrict__ staged, const int* __restrict__ bcur,
        int* __restrict__ offs, int* __restrict__ cols, int Nn, int NB,
        const float* __restrict__ x, const short* __restrict__ Bf1,
        unsigned short* __restrict__ xpb,
        const float* __restrict__ a1s, const float* __restrict__ a1d,
        float* __restrict__ out_as, float* __restrict__ out_ad, int M) {
    __shared__ __align__(16) char smem[SMEM1];
    if ((int)blockIdx.x < NB) {
        buildcsr_body(smem, staged, bcur, offs, cols, Nn, NB, blockIdx.x);
    } else {
        gemm_body<64, 4, 2, 1, false, 16, 256, 2>(
            smem, x, Bf1, xpb, a1s, a1d, out_as, out_ad, M, 128, 8,
            (int)blockIdx.x - NB, 0);
    }
}

// ---------------- layer-2 GEMM (bf16 A, K=128, single phase) ----------------
constexpr int SMEM2 = 64 * (128 + 8) * 2;  // 17408 >= CSZ(64*66*4)
__global__ __launch_bounds__(256, 2) void mfma_gemm2_k(
        const unsigned short* __restrict__ Ab, const short* __restrict__ Bf2,
        unsigned short* __restrict__ Cb,
        const float* __restrict__ a_s, const float* __restrict__ a_d,
        float* __restrict__ out_as, float* __restrict__ out_ad, int M) {
    __shared__ __align__(16) char smem[SMEM2];
    gemm_body<64, 4, 1, 1, true, 8, 128, 1>(
        smem, Ab, Bf2, Cb, a_s, a_d, out_as, out_ad, M, 64, 4, blockIdx.x, 0);
}

// ---------------- single-pass batched aggregation, H=8 C=16 (layer 1) ----------------
// CLOSED: ~4.8 TB/s effective random-gather throughput (fabric ceiling).
template <bool DO_ELU>
__global__ void agg16_k(const unsigned short* __restrict__ xpb,
                        const float* __restrict__ asrc, const float* __restrict__ adst,
                        const int* __restrict__ offs, const int* __restrict__ cols,
                        const float* __restrict__ bias, unsigned short* __restrict__ outb,
                        int N) {
    int gtid = blockIdx.x * blockDim.x + threadIdx.x;
    int n = gtid >> 6;
    if (n >= N) return;
    int lane = threadIdx.x & 63;
    int j = lane >> 3, h = lane & 7;
    const int jb = j << 2;  // bpermute byte addr of (j=0, h=j) lane
    int start = offs[n], end = offs[n + 1];
    const unsigned* xp32 = (const unsigned*)xpb;

    // independent loads first
    unsigned uself = xp32[(size_t)n * 64 + lane];
    float ad_l = adst[n * 8 + h];
    float vs = asrc[n * 8 + h] + ad_l;
    vs = LEAKY(vs);

    // weight-role state (head h): seeded with implicit self-loop
    float m_w = vs;
    float s = (j == 0) ? 1.f : 0.f;
    // feature-role state (head j): acc = self row (weight exp(vs-vs)=1)
    float m_f = bperm_f(jb, vs);
    float a0 = __uint_as_float(uself << 16);
    float a1 = __uint_as_float(uself & 0xffff0000u);

    for (int c0 = start; c0 < end; c0 += 16) {
        int e0 = c0 + j, e1 = c0 + 8 + j;
        bool ok0 = e0 < end, ok1 = e1 < end;
        int sl0 = ok0 ? cols[e0] : 0;
        int sl1 = ok1 ? cols[e1] : 0;
        // ---- issue all 16 row gathers (dep only on cols) ----
        unsigned u[16];
#pragma unroll
        for (int t = 0; t < 8; t++) {
            int srcj = __builtin_amdgcn_readlane(sl0, t * 8);
            u[t] = xp32[(size_t)srcj * 64 + lane];
        }
#pragma unroll
        for (int t = 0; t < 8; t++) {
            int srcj = __builtin_amdgcn_readlane(sl1, t * 8);
            u[8 + t] = xp32[(size_t)srcj * 64 + lane];
        }
        __builtin_amdgcn_sched_barrier(0);
        // ---- weight math while gathers are in flight ----
        float v0 = -1e30f, v1 = -1e30f;
        if (ok0) { v0 = asrc[sl0 * 8 + h] + ad_l; v0 = LEAKY(v0); }
        if (ok1) { v1 = asrc[sl1 * 8 + h] + ad_l; v1 = LEAKY(v1); }
        float cm = fmaxf(v0, v1);
        cm = fmaxf(cm, __shfl_xor(cm, 8, 64));
        cm = fmaxf(cm, __shfl_xor(cm, 16, 64));
        cm = fmaxf(cm, __shfl_xor(cm, 32, 64));
        float mw_new = fmaxf(m_w, cm);
        float w0 = __expf(v0 - mw_new);  // 0 for invalid slots
        float w1 = __expf(v1 - mw_new);
        s = s * __expf(m_w - mw_new) + w0 + w1;
        m_w = mw_new;
        // feature-role rescale (head j)
        float cmF = bperm_f(jb, cm);
        float mf_new = fmaxf(m_f, cmF);
        float scF = __expf(m_f - mf_new);
        m_f = mf_new;
        a0 *= scF; a1 *= scF;
        float wl[16];
#pragma unroll
        for (int t = 0; t < 8; t++) wl[t] = bperm_f(jb + t * 32, w0);
#pragma unroll
        for (int t = 0; t < 8; t++) wl[8 + t] = bperm_f(jb + t * 32, w1);
        // ---- consume ----
#pragma unroll
        for (int t = 0; t < 16; t++) {
            a0 = fmaf(wl[t], __uint_as_float(u[t] << 16), a0);
            a1 = fmaf(wl[t], __uint_as_float(u[t] & 0xffff0000u), a1);
        }
    }
    // finalize: total s per head, then normalize
    s += __shfl_xor(s, 8, 64);
    s += __shfl_xor(s, 16, 64);
    s += __shfl_xor(s, 32, 64);
    float rs = 1.f / (s + 1e-16f);
    float rsF = bperm_f(jb, rs);
    float o0 = a0 * rsF + bias[2 * lane];
    float o1 = a1 * rsF + bias[2 * lane + 1];
    if (DO_ELU) {
        o0 = o0 > 0.f ? o0 : __expf(o0) - 1.f;
        o1 = o1 > 0.f ? o1 : __expf(o1) - 1.f;
    }
    unsigned packed = (unsigned)bf_bits(o0) | ((unsigned)bf_bits(o1) << 16);
    ((unsigned*)outb)[(size_t)n * 64 + lane] = packed;  // row = 128 shorts = 64 uints
}

// ---------------- agg H=8 C=8 (layer 2) + FUSED gemm3/alpha3 ----------------
// R18: alpha3 outputs go to DISTINCT as3/ad3 buffers (R17 aliased them onto
// asrc/adst -> data race).
template <bool DO_ELU>
__global__ void agg8c8_k(const unsigned short* __restrict__ xpb,
                         const float* __restrict__ asrc, const float* __restrict__ adst,
                         const int* __restrict__ offs, const int* __restrict__ cols,
                         const float* __restrict__ bias,
                         const float* __restrict__ W3, const float* __restrict__ a3s,
                         const float* __restrict__ a3d,
                         unsigned short* __restrict__ zout,
                         float* __restrict__ out_as3, float* __restrict__ out_ad3,
                         int N) {
    int gtid = blockIdx.x * blockDim.x + threadIdx.x;
    int n = gtid >> 6;
    if (n >= N) return;
    int lane = threadIdx.x & 63;
    int j = lane >> 3, h = lane & 7;
    int start = offs[n], end = offs[n + 1];
    const unsigned* xp32 = (const unsigned*)xpb;

    int fp = lane & 31;      // feature pair {2fp, 2fp+1}
    int hF = fp >> 2;        // feature-role head
    int half = lane >> 5;
    int sbase = half * 32;

    float ad_l = adst[n * 8 + h];
    float vs = asrc[n * 8 + h] + ad_l;
    vs = LEAKY(vs);

    float m_w = vs;
    float s = (j == 0) ? 1.f : 0.f;
    float m_f = bperm_f(hF * 4, vs);
    float a0 = 0.f, a1 = 0.f;
    if (half == 0) {  // self contribution in half 0 only
        unsigned u = xp32[(size_t)n * 32 + fp];
        a0 = __uint_as_float(u << 16);
        a1 = __uint_as_float(u & 0xffff0000u);
    }

    for (int c0 = start; c0 < end; c0 += 16) {
        int e0 = c0 + j, e1 = c0 + 8 + j;
        bool ok0 = e0 < end, ok1 = e1 < end;
        int sl0 = ok0 ? cols[e0] : 0;
        int sl1 = ok1 ? cols[e1] : 0;
        // ---- issue all 8 row gathers per lane-half (dep only on cols) ----
        int sv[8];
#pragma unroll
        for (int t = 0; t < 4; t++) sv[t] = __builtin_amdgcn_ds_bpermute(sbase + t * 64, sl0);
#pragma unroll
        for (int t = 0; t < 4; t++) sv[4 + t] = __builtin_amdgcn_ds_bpermute(sbase + t * 64, sl1);
        unsigned u[8];
#pragma unroll
        for (int t = 0; t < 8; t++) u[t] = xp32[(size_t)sv[t] * 32 + fp];
        __builtin_amdgcn_sched_barrier(0);
        // ---- weight math while gathers are in flight ----
        float v0 = -1e30f, v1 = -1e30f;
        if (ok0) { v0 = asrc[sl0 * 8 + h] + ad_l; v0 = LEAKY(v0); }
        if (ok1) { v1 = asrc[sl1 * 8 + h] + ad_l; v1 = LEAKY(v1); }
        float cm = fmaxf(v0, v1);
        cm = fmaxf(cm, __shfl_xor(cm, 8, 64));
        cm = fmaxf(cm, __shfl_xor(cm, 16, 64));
        cm = fmaxf(cm, __shfl_xor(cm, 32, 64));
        float mw_new = fmaxf(m_w, cm);
        float w0 = __expf(v0 - mw_new);
        float w1 = __expf(v1 - mw_new);
        s = s * __expf(m_w - mw_new) + w0 + w1;
        m_w = mw_new;
        float cmF = bperm_f(hF * 4, cm);
        float mf_new = fmaxf(m_f, cmF);
        float scF = __expf(m_f - mf_new);
        m_f = mf_new;
        a0 *= scF; a1 *= scF;
        float wl[8];
#pragma unroll
        for (int t = 0; t < 4; t++) wl[t] = bperm_f(sbase + hF * 4 + t * 64, w0);
#pragma unroll
        for (int t = 0; t < 4; t++) wl[4 + t] = bperm_f(sbase + hF * 4 + t * 64, w1);
        // ---- consume ----
#pragma unroll
        for (int t = 0; t < 8; t++) {
            a0 = fmaf(wl[t], __uint_as_float(u[t] << 16), a0);
            a1 = fmaf(wl[t], __uint_as_float(u[t] & 0xffff0000u), a1);
        }
    }
    s += __shfl_xor(s, 8, 64);
    s += __shfl_xor(s, 16, 64);
    s += __shfl_xor(s, 32, 64);
    float rs = 1.f / (s + 1e-16f);
    float rsF = bperm_f(hF * 4, rs);
    // combine halves (same m_f in both halves); both halves now hold full sums
    a0 += __shfl_xor(a0, 32, 64);
    a1 += __shfl_xor(a1, 32, 64);
    float o0 = a0 * rsF + bias[2 * fp];
    float o1 = a1 * rsF + bias[2 * fp + 1];
    if (DO_ELU) {
        o0 = o0 > 0.f ? o0 : __expf(o0) - 1.f;
        o1 = o1 > 0.f ? o1 : __expf(o1) - 1.f;
    }

    // ---- fused layer-3 GEMM (64 -> 10) + alpha3, from f32 h2 in-register ----
    // lane holds h2[2fp], h2[2fp+1]; this half computes z[cbase..cbase+4].
    int cbase = half * 5;
    const float* w3r0 = W3 + (2 * fp) * 10 + cbase;
    const float* w3r1 = W3 + (2 * fp + 1) * 10 + cbase;
    float p0 = o0 * w3r0[0] + o1 * w3r1[0];
    float p1 = o0 * w3r0[1] + o1 * w3r1[1];
    float p2 = o0 * w3r0[2] + o1 * w3r1[2];
    float p3 = o0 * w3r0[3] + o1 * w3r1[3];
    float p4 = o0 * w3r0[4] + o1 * w3r1[4];
#pragma unroll
    for (int off = 1; off < 32; off <<= 1) {  // butterfly within 32-lane half
        p0 += __shfl_xor(p0, off, 64);
        p1 += __shfl_xor(p1, off, 64);
        p2 += __shfl_xor(p2, off, 64);
        p3 += __shfl_xor(p3, off, 64);
        p4 += __shfl_xor(p4, off, 64);
    }
    if (fp < 5) {
        float zv = fp == 0 ? p0 : fp == 1 ? p1 : fp == 2 ? p2 : fp == 3 ? p3 : p4;
        zout[(size_t)n * 10 + cbase + fp] = bf_bits(zv);
    }
    // alpha3 (H=1): partial over this half's 5 cols, combine across halves
    float asum = p0 * a3s[cbase] + p1 * a3s[cbase + 1] + p2 * a3s[cbase + 2]
               + p3 * a3s[cbase + 3] + p4 * a3s[cbase + 4];
    float adsum = p0 * a3d[cbase] + p1 * a3d[cbase + 1] + p2 * a3d[cbase + 2]
                + p3 * a3d[cbase + 3] + p4 * a3d[cbase + 4];
    asum += __shfl_xor(asum, 32, 64);
    adsum += __shfl_xor(adsum, 32, 64);
    if (lane == 0) { out_as3[n] = asum; out_ad3[n] = adsum; }
}

// ---------------- aggregation H=1 C=10 + fused log_softmax (layer 3) ----------------
// R18: evals cache reverted — layer-3 asrc is 400 KB (L2-resident); direct
// re-gather in pass 2 is cheaper than 12.8 MB of cache traffic.
__global__ void agg1h_k(const unsigned short* __restrict__ xpb,
                        const float* __restrict__ asrc, const float* __restrict__ adst,
                        const int* __restrict__ offs, const int* __restrict__ cols,
                        const float* __restrict__ bias, float* __restrict__ out, int N) {
    int gtid = blockIdx.x * blockDim.x + threadIdx.x;
    int n = gtid >> 6;
    if (n >= N) return;
    int lane = threadIdx.x & 63;
    int start = offs[n], end = offs[n + 1];
    float ad = adst[n];
    float vs = asrc[n] + ad;  // implicit self-loop
    vs = LEAKY(vs);

    float m, s;
    if (lane == 0) { m = vs; s = 1.f; } else { m = -1e30f; s = 0.f; }
    for (int e = start + lane; e < end; e += 64) {
        float v = asrc[cols[e]] + ad;
        v = LEAKY(v);
        float mo = fmaxf(m, v);
        s = s * __expf(m - mo) + __expf(v - mo);
        m = mo;
    }
#pragma unroll
    for (int off = 1; off <= 32; off <<= 1) {
        float mo = __shfl_xor(m, off, 64);
        float so = __shfl_xor(s, off, 64);
        float mn = fmaxf(m, mo);
        s = s * __expf(m - mn) + so * __expf(mo - mn);
        m = mn;
    }
    float rs = 1.f / (s + 1e-16f);
    float wself = __expf(vs - m) * rs;

    int j = lane / 10, c = lane - j * 10;
    float acc = 0.f;
    if (j == 0) acc = wself * bf_to_f(xpb[(size_t)n * 10 + c]);  // self term
    for (int c0 = start; c0 < end; c0 += 6) {
        int e = c0 + j;
        if (j < 6 && e < end) {
            int src = cols[e];
            float v = asrc[src] + ad;
            v = LEAKY(v);
            float w = __expf(v - m) * rs;
            acc = fmaf(w, bf_to_f(xpb[(size_t)src * 10 + c]), acc);
        }
    }
    float tot = acc;
#pragma unroll
    for (int k = 1; k < 6; k++) tot += __shfl(acc, lane + 10 * k, 64);

    // fused log_softmax over the 10 classes (valid in lanes 0-9)
    float z = tot + bias[lane < 10 ? lane : 0];
    float mx = -1e30f;
#pragma unroll
    for (int k = 0; k < 10; k++) mx = fmaxf(mx, __shfl(z, k, 64));
    float se = 0.f;
#pragma unroll
    for (int k = 0; k < 10; k++) se += __expf(__shfl(z, k, 64) - mx);
    if (lane < 10) out[(size_t)n * 10 + lane] = z - (__logf(se) + mx);
}

// ---------------- launch ----------------

static inline size_t alignup(size_t x) { return (x + 255) & ~(size_t)255; }

extern "C" void kernel_launch(void* const* d_in, const int* in_sizes, int n_in,
                              void* d_out, int out_size, void* d_ws, size_t ws_size,
                              hipStream_t stream) {
    const float* x   = (const float*)d_in[0];
    const int*   ei  = (const int*)d_in[1];
    const float* W1  = (const float*)d_in[2];
    const float* a1s = (const float*)d_in[3];
    const float* a1d = (const float*)d_in[4];
    const float* b1  = (const float*)d_in[5];
    const float* W2  = (const float*)d_in[6];
    const float* a2s = (const float*)d_in[7];
    const float* a2d = (const float*)d_in[8];
    const float* b2  = (const float*)d_in[9];
    const float* W3  = (const float*)d_in[10];
    const float* a3s = (const float*)d_in[11];
    const float* a3d = (const float*)d_in[12];
    const float* b3  = (const float*)d_in[13];
    float* out = (float*)d_out;

    const int N = in_sizes[0] / 256;
    const int E = in_sizes[1] / 2;
    const int* src = ei;
    const int* dst = ei + E;
    const int NB = (N + 255) >> 8;  // 391 for N=100000 (<= NB_MAX)
    const int PB = (E + 4095) / 4096;

    char* p = (char*)d_ws;
    int* offs    = (int*)p; p += alignup(sizeof(int) * (size_t)(N + 1));
    int* bcur    = (int*)p; p += alignup(sizeof(int) * (size_t)(NB_MAX + 1));
    int* cols    = (int*)p; p += alignup(sizeof(int) * (size_t)E);
    unsigned short* xpb   = (unsigned short*)p; p += alignup(2 * (size_t)N * 128);
    unsigned short* hbufb = (unsigned short*)p; p += alignup(2 * (size_t)N * 128);
    float* xp    = (float*)p; p += alignup(sizeof(float) * (size_t)N * 128);
    float* as_   = (float*)p; p += alignup(sizeof(float) * (size_t)N * 8);
    float* ad_   = (float*)p; p += alignup(sizeof(float) * (size_t)N * 8);
    float* as3_  = (float*)p; p += alignup(sizeof(float) * (size_t)N);
    float* ad3_  = (float*)p; p += alignup(sizeof(float) * (size_t)N);
    short* Bf1   = (short*)p; p += alignup(sizeof(short) * 8 * 8 * 64 * 16);  // K=256,N=128
    short* Bf2   = (short*)p; p += alignup(sizeof(short) * 4 * 4 * 64 * 16);  // K=128,N=64
    // staged bucket regions alias xp (dead after csr_gemm1_k).
    unsigned* staged = (unsigned*)xp;  // NB * BCAP * 4B = 8 MB << 51.2 MB

    const int TB = 256;

    // CSR pass 1 + W pre-pack (fused, independent work)
    hipMemsetAsync(bcur, 0, sizeof(int) * (size_t)(NB + 1), stream);
    part_prep_k<<<PB + 20, 256, 0, stream>>>(
        src, dst, E, NB, bcur, staged, PB, W1, W2, Bf1, Bf2);

    // ---- CSR pass 2 (blocks 0..NB-1) + layer-1 GEMM (rest), fused
    csr_gemm1_k<<<NB + (N + 63) / 64, 256, 0, stream>>>(
        staged, bcur, offs, cols, N, NB, x, Bf1, xpb, a1s, a1d, as_, ad_, N);
    agg16_k<true><<<(N * 64 + TB - 1) / TB, TB, 0, stream>>>(
        xpb, as_, ad_, offs, cols, b1, hbufb, N);

    // ---- layer 2: 128 -> 64 (H=8, C=8), ELU  (A is bf16 agg output)
    mfma_gemm2_k<<<(N + 63) / 64, 256, 0, stream>>>(
        hbufb, Bf2, xpb, a2s, a2d, as_, ad_, N);
    // ---- layer-2 agg + FUSED layer-3 GEMM/alpha (z rows -> hbufb; alpha3
    //      to DISTINCT as3_/ad3_ — no aliasing with asrc/adst)
    agg8c8_k<true><<<(N * 64 + TB - 1) / TB, TB, 0, stream>>>(
        xpb, as_, ad_, offs, cols, b2, W3, a3s, a3d, hbufb, as3_, ad3_, N);

    // ---- layer 3 aggregation + fused log_softmax
    agg1h_k<<<(N * 64 + TB - 1) / TB, TB, 0, stream>>>(
        hbufb, as3_, ad3_, offs, cols, b3, out, N);
}

// Round 11
// 452.651 us; speedup vs baseline: 1.0481x; 1.0481x over previous
//
#include <hip/hip_runtime.h>
#include <hip/hip_bf16.h>
#include <math.h>

// ---------------------------------------------------------------------------
// GAT 3-layer forward on MI355X.
//   R19: REVERT to R16 structure (best measured, 453 us). R17/R18's
//   gemm3-into-agg8c8 fusion was net +20 us (agg8c8 85->91 from 25-shfl
//   butterfly + scattered W3 loads per wave; gemm3_k's real cost was ~5 us,
//   not the ~13 modeled). One change kept: mfma_gemm2_k launch_bounds
//   (256,2)->(256,4) — SMEM2=17.4KB allows it, doubles co-resident blocks
//   covering staging-barrier drains (R15 mechanism).
//   - agg16 CLOSED: ~4.8 TB/s effective random-gather (fabric ceiling),
//     scheduling-invariant across 4 variants. Do not re-attack.
//   R15/R16: K-split L1 staging, part+prep / csr+gemm1 fusions,
//   LDS-C-tile epilogue (R14), gemm3_k MFMA fused alpha (R13),
//   sched_barrier pins (neutral, kept).
// ---------------------------------------------------------------------------

#define LEAKY(v) ((v) > 0.f ? (v) : 0.2f * (v))

typedef __bf16 bf16_t;
typedef __bf16 bf16x8 __attribute__((ext_vector_type(8)));
typedef __bf16 bf16x4 __attribute__((ext_vector_type(4)));
typedef float f32x4 __attribute__((ext_vector_type(4)));
typedef unsigned short u16x8 __attribute__((ext_vector_type(8)));

static __device__ __forceinline__ unsigned short bf_bits(float f) {
    bf16_t b = (bf16_t)f;
    return __builtin_bit_cast(unsigned short, b);
}
static __device__ __forceinline__ float bf_to_f(unsigned short u) {
    return __uint_as_float(((unsigned int)u) << 16);
}
static __device__ __forceinline__ float bperm_f(int byteaddr, float v) {
    return __uint_as_float((unsigned)__builtin_amdgcn_ds_bpermute(byteaddr, (int)__float_as_uint(v)));
}

// ---------------- CSR build: 2-pass bucket sort ----------------
constexpr int NB_MAX = 400;
constexpr int BCAP = 5120;  // capacity per bucket region; mean load 4096

// ---------------- W pre-pack device helpers ----------------
static __device__ __forceinline__ void prep_w_dev(
        const float* __restrict__ W, short* __restrict__ Bfs,
        int K, int N, int NT, int idx) {
    int lane = idx & 63;
    int t = idx >> 6;
    int ntile = t % NT, kstep = t / NT;
    int quad = lane >> 4, nl = lane & 15;
    int n = ntile * 16 + nl;
    bf16_t* dst = (bf16_t*)Bfs + (size_t)idx * 16;
#pragma unroll
    for (int j = 0; j < 8; j++) {
        int k = kstep * 32 + quad * 8 + j;
        float v = W[k * N + n];
        bf16_t h = (bf16_t)v;
        bf16_t l = (bf16_t)(v - (float)h);
        dst[j] = h;
        dst[8 + j] = l;
    }
}
static __device__ __forceinline__ void prep_w3_dev(
        const float* __restrict__ W, short* __restrict__ Bfs, int Nc, int idx) {
    int lane = idx & 63, ks = idx >> 6;
    int quad = lane >> 4, nl = lane & 15;
    bf16_t* dst = (bf16_t*)Bfs + (size_t)idx * 16;
#pragma unroll
    for (int j = 0; j < 8; j++) {
        int k = ks * 32 + quad * 8 + j;
        float v = (nl < Nc) ? W[k * Nc + nl] : 0.f;
        bf16_t h = (bf16_t)v;
        bf16_t l = (bf16_t)(v - (float)h);
        dst[j] = h;
        dst[8 + j] = l;
    }
}

// ---------------- fused: edge partition + W pre-pack ----------------
__global__ __launch_bounds__(256) void part_prep_k(
        const int* __restrict__ src, const int* __restrict__ dst, int E, int NB,
        int* __restrict__ bcur, unsigned* __restrict__ staged, int PB,
        const float* __restrict__ W1, const float* __restrict__ W2,
        const float* __restrict__ W3, short* __restrict__ Bf1,
        short* __restrict__ Bf2, short* __restrict__ Bf3) {
    __shared__ int hist[NB_MAX];
    __shared__ int bstart[NB_MAX + 1];
    __shared__ int cur[NB_MAX];
    __shared__ int gbase[NB_MAX];
    __shared__ unsigned words[4096];
    __shared__ unsigned short bidl[4096];
    int tid = threadIdx.x;

    if ((int)blockIdx.x >= PB) {  // ---- prep branch ----
        int idx = ((int)blockIdx.x - PB) * 256 + tid;
        if (idx < 4096) prep_w_dev(W1, Bf1, 256, 128, 8, idx);
        else if (idx < 5120) prep_w_dev(W2, Bf2, 128, 64, 4, idx - 4096);
        else if (idx < 5248) prep_w3_dev(W3, Bf3, 10, idx - 5120);
        return;
    }

    int e0 = blockIdx.x * 4096;
    int cnt = E - e0; if (cnt > 4096) cnt = 4096;
    if (cnt <= 0) return;

    for (int b = tid; b < NB; b += 256) hist[b] = 0;
    __syncthreads();
    for (int i = tid; i < cnt; i += 256) atomicAdd(&hist[dst[e0 + i] >> 8], 1);
    __syncthreads();
    // wave-0 parallel exclusive scan over NB entries
    if (tid < 64) {
        int lane = tid;
        int run = 0;
        for (int b0 = 0; b0 < NB; b0 += 64) {
            int bb = b0 + lane;
            int v = (bb < NB) ? hist[bb] : 0;
            int sc = v;
            for (int off = 1; off < 64; off <<= 1) {
                int t2 = __shfl_up(sc, off, 64);
                if (lane >= off) sc += t2;
            }
            if (bb < NB) bstart[bb] = run + sc - v;
            run += __shfl(sc, 63, 64);
        }
        if (lane == 0) bstart[NB] = run;
    }
    __syncthreads();
    for (int b = tid; b < NB; b += 256) {
        cur[b] = bstart[b];
        gbase[b] = hist[b] ? atomicAdd(&bcur[b], hist[b]) : 0;
    }
    __syncthreads();
    // group into LDS by bucket, remember bucket id per slot
    for (int i = tid; i < cnt; i += 256) {
        int s = src[e0 + i], d = dst[e0 + i];
        int b = d >> 8;
        unsigned w = (unsigned)s | ((unsigned)(d & 255) << 17);
        int p = atomicAdd(&cur[b], 1);
        words[p] = w;
        bidl[p] = (unsigned short)b;
    }
    __syncthreads();
    // linear sweep -> coalesced runs into global bucket regions
    for (int i = tid; i < cnt; i += 256) {
        int b = bidl[i];
        staged[(size_t)b * BCAP + gbase[b] + (i - bstart[b])] = words[i];
    }
}

// ---------------- buildcsr body (runs inside fused csr_gemm1_k) ----------------
static __device__ void buildcsr_body(
        char* smem, const unsigned* __restrict__ staged, const int* __restrict__ bcur,
        int* __restrict__ offs, int* __restrict__ cols, int N, int NB, int b) {
    int* h    = (int*)smem;
    int* hs   = h + 256;
    int* curl = hs + 256;
    int* colsl = curl + 256;
    int* base_p = colsl + BCAP;
    int tid = threadIdx.x;
    int n0 = b << 8;
    int ecnt = bcur[b];
    const unsigned* sb = staged + (size_t)b * BCAP;

    h[tid] = 0;
    if (tid < 64) {  // base_g = sum(bcur[0..b))
        int acc2 = 0;
        for (int i = tid; i < b; i += 64) acc2 += bcur[i];
        for (int off = 1; off < 64; off <<= 1) acc2 += __shfl_xor(acc2, off, 64);
        if (tid == 0) *base_p = acc2;
    }
    __syncthreads();
    int base_g = *base_p;
    for (int i = tid; i < ecnt; i += 256) atomicAdd(&h[sb[i] >> 17], 1);
    __syncthreads();
    int val = h[tid];
    hs[tid] = val; __syncthreads();
    for (int off = 1; off < 256; off <<= 1) {
        int t = (tid >= off) ? hs[tid - off] : 0;
        __syncthreads();
        hs[tid] += t;
        __syncthreads();
    }
    int excl = hs[tid] - val;
    curl[tid] = excl;
    if (n0 + tid < N) offs[n0 + tid] = base_g + excl;
    if (b == NB - 1 && tid == 0) offs[N] = base_g + ecnt;
    __syncthreads();
    for (int i = tid; i < ecnt; i += 256) {
        unsigned w = sb[i];
        int p = atomicAdd(&curl[w >> 17], 1);
        colsl[p] = (int)(w & 0x1FFFFu);
    }
    __syncthreads();
    for (int i = tid; i < ecnt; i += 256) cols[base_g + i] = colsl[i];
}

// ---------------- split-bf16 MFMA GEMM body (K-split staging + epilogue v2) ----------------
template <int BM, int WMT, int WNT, int NWM, bool ABF16, int CHEAD, int K, int NPH>
static __device__ __forceinline__ void gemm_body(
        char* smem,
        const void* __restrict__ Av, const short* __restrict__ Bfs,
        unsigned short* __restrict__ Cb,
        const float* __restrict__ a_s, const float* __restrict__ a_d,
        float* __restrict__ out_as, float* __restrict__ out_ad,
        int M, int N, int NT, int bx, int by) {
    constexpr int NWN = 4 / NWM;
    constexpr int BN = 16 * WNT * NWN;
    constexpr int KPH = K / NPH;     // K per staging phase
    constexpr int KPP = KPH + 8;     // +8 bf16 pad: breaks bank aliasing
    constexpr int BNP = BN + 2;      // f32 C-tile pad
    bf16_t* As_hi = (bf16_t*)smem;
    bf16_t* As_lo = As_hi + (ABF16 ? 0 : (size_t)BM * KPP);
    float* Ct = (float*)smem;
    const bf16_t* Bf = (const bf16_t*)Bfs;

    int tid = threadIdx.x;
    int wave = tid >> 6, lane = tid & 63;
    int quad = lane >> 4, l16 = lane & 15;
    int wm = wave % NWM, wn = wave / NWM;
    int row0 = bx * BM;
    int ntile0 = by * (BN / 16) + wn * WNT;

    f32x4 acc[WMT][WNT];
#pragma unroll
    for (int i = 0; i < WMT; i++)
#pragma unroll
        for (int j = 0; j < WNT; j++) acc[i][j] = (f32x4){0.f, 0.f, 0.f, 0.f};

#pragma unroll
    for (int phase = 0; phase < NPH; phase++) {
        if (phase) __syncthreads();  // previous compute's LDS reads done
        // ---- stage this K-phase: all loads issued before conversion ----
        if constexpr (!ABF16) {
            constexpr int CHUNKS = BM * KPH * 4 / (16 * 256);
            const float* A = (const float*)Av;
            f32x4 tmp[CHUNKS];
#pragma unroll
            for (int c = 0; c < CHUNKS; c++) {
                int ci = c * 256 + tid;
                int fi = ci * 4;
                int row = fi / KPH, k = fi % KPH;
                int grow = row0 + row;
                tmp[c] = (f32x4){0.f, 0.f, 0.f, 0.f};
                if (grow < M) tmp[c] = *(const f32x4*)(A + (size_t)grow * K + phase * KPH + k);
            }
#pragma unroll
            for (int c = 0; c < CHUNKS; c++) {
                int ci = c * 256 + tid;
                int fi = ci * 4;
                int row = fi / KPH, k = fi % KPH;
                bf16x4 h, l;
#pragma unroll
                for (int j = 0; j < 4; j++) {
                    bf16_t hh = (bf16_t)tmp[c][j];
                    h[j] = hh;
                    l[j] = (bf16_t)(tmp[c][j] - (float)hh);
                }
                *(bf16x4*)&As_hi[row * KPP + k] = h;
                *(bf16x4*)&As_lo[row * KPP + k] = l;
            }
        } else {
            constexpr int CHUNKS = BM * KPH * 2 / (16 * 256);
            const unsigned short* A = (const unsigned short*)Av;
            u16x8 tmp[CHUNKS];
#pragma unroll
            for (int c = 0; c < CHUNKS; c++) {
                int ci = c * 256 + tid;
                int ei = ci * 8;
                int row = ei / KPH, k = ei % KPH;
                int grow = row0 + row;
                tmp[c] = (u16x8){0, 0, 0, 0, 0, 0, 0, 0};
                if (grow < M) tmp[c] = *(const u16x8*)(A + (size_t)grow * K + phase * KPH + k);
            }
#pragma unroll
            for (int c = 0; c < CHUNKS; c++) {
                int ci = c * 256 + tid;
                int ei = ci * 8;
                int row = ei / KPH, k = ei % KPH;
                *(u16x8*)&As_hi[row * KPP + k] = tmp[c];
            }
        }
        __syncthreads();

        // ---- compute this K-phase (barrier-free) ----
#pragma unroll
        for (int ks = 0; ks < KPH / 32; ks++) {
            int ksg = phase * (KPH / 32) + ks;
            bf16x8 ah[WMT], al[WMT];
#pragma unroll
            for (int i = 0; i < WMT; i++) {
                int rowl = wm * (WMT * 16) + i * 16 + l16;
                ah[i] = *(const bf16x8*)&As_hi[rowl * KPP + ks * 32 + quad * 8];
                if (!ABF16) al[i] = *(const bf16x8*)&As_lo[rowl * KPP + ks * 32 + quad * 8];
            }
            bf16x8 bh[WNT], bl[WNT];
#pragma unroll
            for (int j = 0; j < WNT; j++) {
                size_t base = ((size_t)(ksg * NT + ntile0 + j) * 64 + lane) * 16;
                bh[j] = *(const bf16x8*)&Bf[base];
                bl[j] = *(const bf16x8*)&Bf[base + 8];
            }
#pragma unroll
            for (int i = 0; i < WMT; i++)
#pragma unroll
                for (int j = 0; j < WNT; j++) {
                    acc[i][j] = __builtin_amdgcn_mfma_f32_16x16x32_bf16(ah[i], bh[j], acc[i][j], 0, 0, 0);
                    if (!ABF16)
                        acc[i][j] = __builtin_amdgcn_mfma_f32_16x16x32_bf16(al[i], bh[j], acc[i][j], 0, 0, 0);
                    acc[i][j] = __builtin_amdgcn_mfma_f32_16x16x32_bf16(ah[i], bl[j], acc[i][j], 0, 0, 0);
                }
        }
    }

    // ---- epilogue v2: acc -> LDS f32 C-tile, then alpha + coalesced C ----
    __syncthreads();  // all As reads done before overwrite
#pragma unroll
    for (int i = 0; i < WMT; i++) {
        int rbase = wm * (WMT * 16) + i * 16 + quad * 4;  // block-local row
#pragma unroll
        for (int j = 0; j < WNT; j++) {
            int lcol = (wn * WNT + j) * 16 + l16;          // block-local col
#pragma unroll
            for (int r2 = 0; r2 < 4; r2++)
                Ct[(size_t)(rbase + r2) * BNP + lcol] = acc[i][j][r2];
        }
    }
    __syncthreads();

    // phase 2a: alpha — BM x (BN/CHEAD) outputs, contiguous LDS reads
    constexpr int HB = BN / CHEAD;
    const int colbase = by * BN;
    const int Hh = N / CHEAD;
#pragma unroll
    for (int o = 0; o < (BM * HB + 255) / 256; o++) {
        int idx = o * 256 + tid;
        if (idx < BM * HB) {
            int row = idx & (BM - 1);
            int hd = idx / BM;   // wave-uniform -> scalar a_s/a_d loads
            const float* crow = Ct + (size_t)row * BNP + hd * CHEAD;
            float ss = 0.f, sd = 0.f;
#pragma unroll
            for (int c = 0; c < CHEAD; c++) {
                float v = crow[c];
                ss = fmaf(v, a_s[colbase + hd * CHEAD + c], ss);
                sd = fmaf(v, a_d[colbase + hd * CHEAD + c], sd);
            }
            int grow = row0 + row;
            if (grow < M) {
                out_as[(size_t)grow * Hh + by * HB + hd] = ss;
                out_ad[(size_t)grow * Hh + by * HB + hd] = sd;
            }
        }
    }

    // phase 2b: C store — packed 2xbf16, coalesced 4B/lane
    constexpr int CU2 = BM * BN / 2;  // uint count (multiple of 256 here)
#pragma unroll
    for (int o = 0; o < CU2 / 256; o++) {
        int idx = o * 256 + tid;
        int row = idx / (BN / 2);
        int uc = idx - row * (BN / 2);
        float v0 = Ct[(size_t)row * BNP + uc * 2];
        float v1 = Ct[(size_t)row * BNP + uc * 2 + 1];
        unsigned pk = (unsigned)bf_bits(v0) | ((unsigned)bf_bits(v1) << 16);
        int grow = row0 + row;
        if (grow < M)
            ((unsigned*)Cb)[((size_t)grow * N + colbase) / 2 + uc] = pk;
    }
}

// ---------------- fused: buildcsr + layer-1 GEMM ----------------
constexpr int SMEM1 = 64 * (128 + 8) * 2 * 2;  // 34816 >= max(ASZ, CSZ, CSR)
__global__ __launch_bounds__(256, 3) void csr_gemm1_k(
        const unsigned* __restrict__ staged, const int* __restrict__ bcur,
        int* __restrict__ offs, int* __restrict__ cols, int Nn, int NB,
        const float* __restrict__ x, const short* __restrict__ Bf1,
        unsigned short* __restrict__ xpb,
        const float* __restrict__ a1s, const float* __restrict__ a1d,
        float* __restrict__ out_as, float* __restrict__ out_ad, int M) {
    __shared__ __align__(16) char smem[SMEM1];
    if ((int)blockIdx.x < NB) {
        buildcsr_body(smem, staged, bcur, offs, cols, Nn, NB, blockIdx.x);
    } else {
        gemm_body<64, 4, 2, 1, false, 16, 256, 2>(
            smem, x, Bf1, xpb, a1s, a1d, out_as, out_ad, M, 128, 8,
            (int)blockIdx.x - NB, 0);
    }
}

// ---------------- layer-2 GEMM (bf16 A, K=128, single phase) ----------------
// R19: launch_bounds (256,2)->(256,4): 17.4KB LDS permits 4 blocks/CU;
// more co-resident blocks cover each other's staging-barrier drains.
constexpr int SMEM2 = 64 * (128 + 8) * 2;  // 17408 >= CSZ(64*66*4)
__global__ __launch_bounds__(256, 4) void mfma_gemm2_k(
        const unsigned short* __restrict__ Ab, const short* __restrict__ Bf2,
        unsigned short* __restrict__ Cb,
        const float* __restrict__ a_s, const float* __restrict__ a_d,
        float* __restrict__ out_as, float* __restrict__ out_ad, int M) {
    __shared__ __align__(16) char smem[SMEM2];
    gemm_body<64, 4, 1, 1, true, 8, 128, 1>(
        smem, Ab, Bf2, Cb, a_s, a_d, out_as, out_ad, M, 64, 4, blockIdx.x, 0);
}

// ---------------- layer-3 MFMA GEMM + fused alpha (K=64, N=10 pad 16) ----------------
__global__ __launch_bounds__(256) void gemm3_k(
        const unsigned short* __restrict__ Ab, const short* __restrict__ Bfs,
        unsigned short* __restrict__ Cb,
        const float* __restrict__ a_s, const float* __restrict__ a_d,
        float* __restrict__ out_as, float* __restrict__ out_ad, int M) {
    const bf16_t* Bf = (const bf16_t*)Bfs;
    int tid = threadIdx.x;
    int wave = tid >> 6, lane = tid & 63;
    int quad = lane >> 4, l16 = lane & 15;
    int grow0 = blockIdx.x * 64 + wave * 16;

    bf16x8 bh[2], bl[2];
#pragma unroll
    for (int ks = 0; ks < 2; ks++) {
        size_t base = (size_t)(ks * 64 + lane) * 16;
        bh[ks] = *(const bf16x8*)&Bf[base];
        bl[ks] = *(const bf16x8*)&Bf[base + 8];
    }

    int arow = grow0 + l16; if (arow >= M) arow = M - 1;  // clamp; outputs guarded
    f32x4 acc = (f32x4){0.f, 0.f, 0.f, 0.f};
#pragma unroll
    for (int ks = 0; ks < 2; ks++) {
        bf16x8 a = *(const bf16x8*)(Ab + (size_t)arow * 64 + ks * 32 + quad * 8);
        acc = __builtin_amdgcn_mfma_f32_16x16x32_bf16(a, bh[ks], acc, 0, 0, 0);
        acc = __builtin_amdgcn_mfma_f32_16x16x32_bf16(a, bl[ks], acc, 0, 0, 0);
    }

    bool colv = l16 < 10;
    float cs = colv ? a_s[l16] : 0.f;
    float cd = colv ? a_d[l16] : 0.f;
    float ps[4], pd[4];
#pragma unroll
    for (int r = 0; r < 4; r++) { ps[r] = acc[r] * cs; pd[r] = acc[r] * cd; }
#pragma unroll
    for (int off = 1; off < 16; off <<= 1) {
#pragma unroll
        for (int r = 0; r < 4; r++) {
            ps[r] += __shfl_xor(ps[r], off, 64);
            pd[r] += __shfl_xor(pd[r], off, 64);
        }
    }
#pragma unroll
    for (int r = 0; r < 4; r++) {
        int grow = grow0 + quad * 4 + r;
        if (grow < M) {
            if (colv) Cb[(size_t)grow * 10 + l16] = bf_bits(acc[r]);
            if (l16 == 0) { out_as[grow] = ps[r]; out_ad[grow] = pd[r]; }
        }
    }
}

// ---------------- single-pass batched aggregation, H=8 C=16 (layer 1) ----------------
// CLOSED: ~4.8 TB/s effective random-gather throughput (fabric ceiling).
template <bool DO_ELU>
__global__ void agg16_k(const unsigned short* __restrict__ xpb,
                        const float* __restrict__ asrc, const float* __restrict__ adst,
                        const int* __restrict__ offs, const int* __restrict__ cols,
                        const float* __restrict__ bias, unsigned short* __restrict__ outb,
                        int N) {
    int gtid = blockIdx.x * blockDim.x + threadIdx.x;
    int n = gtid >> 6;
    if (n >= N) return;
    int lane = threadIdx.x & 63;
    int j = lane >> 3, h = lane & 7;
    const int jb = j << 2;  // bpermute byte addr of (j=0, h=j) lane
    int start = offs[n], end = offs[n + 1];
    const unsigned* xp32 = (const unsigned*)xpb;

    // independent loads first
    unsigned uself = xp32[(size_t)n * 64 + lane];
    float ad_l = adst[n * 8 + h];
    float vs = asrc[n * 8 + h] + ad_l;
    vs = LEAKY(vs);

    // weight-role state (head h): seeded with implicit self-loop
    float m_w = vs;
    float s = (j == 0) ? 1.f : 0.f;
    // feature-role state (head j): acc = self row (weight exp(vs-vs)=1)
    float m_f = bperm_f(jb, vs);
    float a0 = __uint_as_float(uself << 16);
    float a1 = __uint_as_float(uself & 0xffff0000u);

    for (int c0 = start; c0 < end; c0 += 16) {
        int e0 = c0 + j, e1 = c0 + 8 + j;
        bool ok0 = e0 < end, ok1 = e1 < end;
        int sl0 = ok0 ? cols[e0] : 0;
        int sl1 = ok1 ? cols[e1] : 0;
        // ---- issue all 16 row gathers (dep only on cols) ----
        unsigned u[16];
#pragma unroll
        for (int t = 0; t < 8; t++) {
            int srcj = __builtin_amdgcn_readlane(sl0, t * 8);
            u[t] = xp32[(size_t)srcj * 64 + lane];
        }
#pragma unroll
        for (int t = 0; t < 8; t++) {
            int srcj = __builtin_amdgcn_readlane(sl1, t * 8);
            u[8 + t] = xp32[(size_t)srcj * 64 + lane];
        }
        __builtin_amdgcn_sched_barrier(0);
        // ---- weight math while gathers are in flight ----
        float v0 = -1e30f, v1 = -1e30f;
        if (ok0) { v0 = asrc[sl0 * 8 + h] + ad_l; v0 = LEAKY(v0); }
        if (ok1) { v1 = asrc[sl1 * 8 + h] + ad_l; v1 = LEAKY(v1); }
        float cm = fmaxf(v0, v1);
        cm = fmaxf(cm, __shfl_xor(cm, 8, 64));
        cm = fmaxf(cm, __shfl_xor(cm, 16, 64));
        cm = fmaxf(cm, __shfl_xor(cm, 32, 64));
        float mw_new = fmaxf(m_w, cm);
        float w0 = __expf(v0 - mw_new);  // 0 for invalid slots
        float w1 = __expf(v1 - mw_new);
        s = s * __expf(m_w - mw_new) + w0 + w1;
        m_w = mw_new;
        // feature-role rescale (head j)
        float cmF = bperm_f(jb, cm);
        float mf_new = fmaxf(m_f, cmF);
        float scF = __expf(m_f - mf_new);
        m_f = mf_new;
        a0 *= scF; a1 *= scF;
        float wl[16];
#pragma unroll
        for (int t = 0; t < 8; t++) wl[t] = bperm_f(jb + t * 32, w0);
#pragma unroll
        for (int t = 0; t < 8; t++) wl[8 + t] = bperm_f(jb + t * 32, w1);
        // ---- consume ----
#pragma unroll
        for (int t = 0; t < 16; t++) {
            a0 = fmaf(wl[t], __uint_as_float(u[t] << 16), a0);
            a1 = fmaf(wl[t], __uint_as_float(u[t] & 0xffff0000u), a1);
        }
    }
    // finalize: total s per head, then normalize
    s += __shfl_xor(s, 8, 64);
    s += __shfl_xor(s, 16, 64);
    s += __shfl_xor(s, 32, 64);
    float rs = 1.f / (s + 1e-16f);
    float rsF = bperm_f(jb, rs);
    float o0 = a0 * rsF + bias[2 * lane];
    float o1 = a1 * rsF + bias[2 * lane + 1];
    if (DO_ELU) {
        o0 = o0 > 0.f ? o0 : __expf(o0) - 1.f;
        o1 = o1 > 0.f ? o1 : __expf(o1) - 1.f;
    }
    unsigned packed = (unsigned)bf_bits(o0) | ((unsigned)bf_bits(o1) << 16);
    ((unsigned*)outb)[(size_t)n * 64 + lane] = packed;  // row = 128 shorts = 64 uints
}

// ---------------- single-pass batched aggregation, H=8 C=8 (layer 2) ----------------
template <bool DO_ELU>
__global__ void agg8c8_k(const unsigned short* __restrict__ xpb,
                         const float* __restrict__ asrc, const float* __restrict__ adst,
                         const int* __restrict__ offs, const int* __restrict__ cols,
                         const float* __restrict__ bias, unsigned short* __restrict__ outb,
                         int N) {
    int gtid = blockIdx.x * blockDim.x + threadIdx.x;
    int n = gtid >> 6;
    if (n >= N) return;
    int lane = threadIdx.x & 63;
    int j = lane >> 3, h = lane & 7;
    int start = offs[n], end = offs[n + 1];
    const unsigned* xp32 = (const unsigned*)xpb;

    int fp = lane & 31;      // feature pair {2fp, 2fp+1}
    int hF = fp >> 2;        // feature-role head
    int half = lane >> 5;
    int sbase = half * 32;

    float ad_l = adst[n * 8 + h];
    float vs = asrc[n * 8 + h] + ad_l;
    vs = LEAKY(vs);

    float m_w = vs;
    float s = (j == 0) ? 1.f : 0.f;
    float m_f = bperm_f(hF * 4, vs);
    float a0 = 0.f, a1 = 0.f;
    if (half == 0) {  // self contribution in half 0 only
        unsigned u = xp32[(size_t)n * 32 + fp];
        a0 = __uint_as_float(u << 16);
        a1 = __uint_as_float(u & 0xffff0000u);
    }

    for (int c0 = start; c0 < end; c0 += 16) {
        int e0 = c0 + j, e1 = c0 + 8 + j;
        bool ok0 = e0 < end, ok1 = e1 < end;
        int sl0 = ok0 ? cols[e0] : 0;
        int sl1 = ok1 ? cols[e1] : 0;
        // ---- issue all 8 row gathers per lane-half (dep only on cols) ----
        int sv[8];
#pragma unroll
        for (int t = 0; t < 4; t++) sv[t] = __builtin_amdgcn_ds_bpermute(sbase + t * 64, sl0);
#pragma unroll
        for (int t = 0; t < 4; t++) sv[4 + t] = __builtin_amdgcn_ds_bpermute(sbase + t * 64, sl1);
        unsigned u[8];
#pragma unroll
        for (int t = 0; t < 8; t++) u[t] = xp32[(size_t)sv[t] * 32 + fp];
        __builtin_amdgcn_sched_barrier(0);
        // ---- weight math while gathers are in flight ----
        float v0 = -1e30f, v1 = -1e30f;
        if (ok0) { v0 = asrc[sl0 * 8 + h] + ad_l; v0 = LEAKY(v0); }
        if (ok1) { v1 = asrc[sl1 * 8 + h] + ad_l; v1 = LEAKY(v1); }
        float cm = fmaxf(v0, v1);
        cm = fmaxf(cm, __shfl_xor(cm, 8, 64));
        cm = fmaxf(cm, __shfl_xor(cm, 16, 64));
        cm = fmaxf(cm, __shfl_xor(cm, 32, 64));
        float mw_new = fmaxf(m_w, cm);
        float w0 = __expf(v0 - mw_new);
        float w1 = __expf(v1 - mw_new);
        s = s * __expf(m_w - mw_new) + w0 + w1;
        m_w = mw_new;
        float cmF = bperm_f(hF * 4, cm);
        float mf_new = fmaxf(m_f, cmF);
        float scF = __expf(m_f - mf_new);
        m_f = mf_new;
        a0 *= scF; a1 *= scF;
        float wl[8];
#pragma unroll
        for (int t = 0; t < 4; t++) wl[t] = bperm_f(sbase + hF * 4 + t * 64, w0);
#pragma unroll
        for (int t = 0; t < 4; t++) wl[4 + t] = bperm_f(sbase + hF * 4 + t * 64, w1);
        // ---- consume ----
#pragma unroll
        for (int t = 0; t < 8; t++) {
            a0 = fmaf(wl[t], __uint_as_float(u[t] << 16), a0);
            a1 = fmaf(wl[t], __uint_as_float(u[t] & 0xffff0000u), a1);
        }
    }
    s += __shfl_xor(s, 8, 64);
    s += __shfl_xor(s, 16, 64);
    s += __shfl_xor(s, 32, 64);
    float rs = 1.f / (s + 1e-16f);
    float rsF = bperm_f(hF * 4, rs);
    // combine halves (same m_f in both halves), then normalize
    a0 += __shfl_xor(a0, 32, 64);
    a1 += __shfl_xor(a1, 32, 64);
    if (half == 0) {
        float o0 = a0 * rsF + bias[2 * fp];
        float o1 = a1 * rsF + bias[2 * fp + 1];
        if (DO_ELU) {
            o0 = o0 > 0.f ? o0 : __expf(o0) - 1.f;
            o1 = o1 > 0.f ? o1 : __expf(o1) - 1.f;
        }
        unsigned packed = (unsigned)bf_bits(o0) | ((unsigned)bf_bits(o1) << 16);
        ((unsigned*)outb)[(size_t)n * 32 + fp] = packed;  // row = 64 shorts = 32 uints
    }
}

// ---------------- aggregation H=1 C=10 + fused log_softmax (layer 3) ----------------
__global__ void agg1h_k(const unsigned short* __restrict__ xpb,
                        const float* __restrict__ asrc, const float* __restrict__ adst,
                        const int* __restrict__ offs, const int* __restrict__ cols,
                        const float* __restrict__ bias, float* __restrict__ out, int N) {
    int gtid = blockIdx.x * blockDim.x + threadIdx.x;
    int n = gtid >> 6;
    if (n >= N) return;
    int lane = threadIdx.x & 63;
    int start = offs[n], end = offs[n + 1];
    float ad = adst[n];
    float vs = asrc[n] + ad;  // implicit self-loop
    vs = LEAKY(vs);

    float m, s;
    if (lane == 0) { m = vs; s = 1.f; } else { m = -1e30f; s = 0.f; }
    for (int e = start + lane; e < end; e += 64) {
        float v = asrc[cols[e]] + ad;
        v = LEAKY(v);
        float mo = fmaxf(m, v);
        s = s * __expf(m - mo) + __expf(v - mo);
        m = mo;
    }
#pragma unroll
    for (int off = 1; off <= 32; off <<= 1) {
        float mo = __shfl_xor(m, off, 64);
        float so = __shfl_xor(s, off, 64);
        float mn = fmaxf(m, mo);
        s = s * __expf(m - mn) + so * __expf(mo - mn);
        m = mn;
    }
    float rs = 1.f / (s + 1e-16f);
    float wself = __expf(vs - m) * rs;

    int j = lane / 10, c = lane - j * 10;
    float acc = 0.f;
    if (j == 0) acc = wself * bf_to_f(xpb[(size_t)n * 10 + c]);  // self term
    for (int c0 = start; c0 < end; c0 += 6) {
        int e = c0 + j;
        if (j < 6 && e < end) {
            int src = cols[e];
            float v = asrc[src] + ad;
            v = LEAKY(v);
            float w = __expf(v - m) * rs;
            acc = fmaf(w, bf_to_f(xpb[(size_t)src * 10 + c]), acc);
        }
    }
    float tot = acc;
#pragma unroll
    for (int k = 1; k < 6; k++) tot += __shfl(acc, lane + 10 * k, 64);

    // fused log_softmax over the 10 classes (valid in lanes 0-9)
    float z = tot + bias[lane < 10 ? lane : 0];
    float mx = -1e30f;
#pragma unroll
    for (int k = 0; k < 10; k++) mx = fmaxf(mx, __shfl(z, k, 64));
    float se = 0.f;
#pragma unroll
    for (int k = 0; k < 10; k++) se += __expf(__shfl(z, k, 64) - mx);
    if (lane < 10) out[(size_t)n * 10 + lane] = z - (__logf(se) + mx);
}

// ---------------- launch ----------------

static inline size_t alignup(size_t x) { return (x + 255) & ~(size_t)255; }

extern "C" void kernel_launch(void* const* d_in, const int* in_sizes, int n_in,
                              void* d_out, int out_size, void* d_ws, size_t ws_size,
                              hipStream_t stream) {
    const float* x   = (const float*)d_in[0];
    const int*   ei  = (const int*)d_in[1];
    const float* W1  = (const float*)d_in[2];
    const float* a1s = (const float*)d_in[3];
    const float* a1d = (const float*)d_in[4];
    const float* b1  = (const float*)d_in[5];
    const float* W2  = (const float*)d_in[6];
    const float* a2s = (const float*)d_in[7];
    const float* a2d = (const float*)d_in[8];
    const float* b2  = (const float*)d_in[9];
    const float* W3  = (const float*)d_in[10];
    const float* a3s = (const float*)d_in[11];
    const float* a3d = (const float*)d_in[12];
    const float* b3  = (const float*)d_in[13];
    float* out = (float*)d_out;

    const int N = in_sizes[0] / 256;
    const int E = in_sizes[1] / 2;
    const int* src = ei;
    const int* dst = ei + E;
    const int NB = (N + 255) >> 8;  // 391 for N=100000 (<= NB_MAX)
    const int PB = (E + 4095) / 4096;

    char* p = (char*)d_ws;
    int* offs    = (int*)p; p += alignup(sizeof(int) * (size_t)(N + 1));
    int* bcur    = (int*)p; p += alignup(sizeof(int) * (size_t)(NB_MAX + 1));
    int* cols    = (int*)p; p += alignup(sizeof(int) * (size_t)E);
    unsigned short* xpb   = (unsigned short*)p; p += alignup(2 * (size_t)N * 128);
    unsigned short* hbufb = (unsigned short*)p; p += alignup(2 * (size_t)N * 128);
    float* xp    = (float*)p; p += alignup(sizeof(float) * (size_t)N * 128);
    float* as_   = (float*)p; p += alignup(sizeof(float) * (size_t)N * 8);
    float* ad_   = (float*)p; p += alignup(sizeof(float) * (size_t)N * 8);
    short* Bf1   = (short*)p; p += alignup(sizeof(short) * 8 * 8 * 64 * 16);  // K=256,N=128
    short* Bf2   = (short*)p; p += alignup(sizeof(short) * 4 * 4 * 64 * 16);  // K=128,N=64
    short* Bf3   = (short*)p; p += alignup(sizeof(short) * 2 * 1 * 64 * 16);  // K=64,N=16(pad)
    // staged bucket regions alias xp (xp is dead since R13's fused gemm3);
    // CSR build (csr_gemm1_k blocks < NB) only reads staged while gemm blocks
    // write xpb/as_/ad_ — distinct buffers.
    unsigned* staged = (unsigned*)xp;  // NB * BCAP * 4B = 8 MB << 51.2 MB

    const int TB = 256;

    // CSR pass 1 + W pre-pack (fused, independent work)
    hipMemsetAsync(bcur, 0, sizeof(int) * (size_t)(NB + 1), stream);
    part_prep_k<<<PB + 21, 256, 0, stream>>>(
        src, dst, E, NB, bcur, staged, PB, W1, W2, W3, Bf1, Bf2, Bf3);

    // ---- CSR pass 2 (blocks 0..NB-1) + layer-1 GEMM (rest), fused
    csr_gemm1_k<<<NB + (N + 63) / 64, 256, 0, stream>>>(
        staged, bcur, offs, cols, N, NB, x, Bf1, xpb, a1s, a1d, as_, ad_, N);
    agg16_k<true><<<(N * 64 + TB - 1) / TB, TB, 0, stream>>>(
        xpb, as_, ad_, offs, cols, b1, hbufb, N);

    // ---- layer 2: 128 -> 64 (H=8, C=8), ELU  (A is bf16 agg output)
    mfma_gemm2_k<<<(N + 63) / 64, 256, 0, stream>>>(
        hbufb, Bf2, xpb, a2s, a2d, as_, ad_, N);
    agg8c8_k<true><<<(N * 64 + TB - 1) / TB, TB, 0, stream>>>(
        xpb, as_, ad_, offs, cols, b2, hbufb, N);

    // ---- layer 3: 64 -> 10 (H=1, C=10) MFMA + fused alpha, then agg + log_softmax
    gemm3_k<<<(N + 63) / 64, 256, 0, stream>>>(
        hbufb, Bf3, xpb, a3s, a3d, as_, ad_, N);
    agg1h_k<<<(N * 64 + TB - 1) / TB, TB, 0, stream>>>(
        xpb, as_, ad_, offs, cols, b3, out, N);
}